// Round 18
// baseline (381.618 us; speedup 1.0000x reference)
//
#include <hip/hip_runtime.h>
#include <hip/hip_bf16.h>
#include <stdint.h>

// EncoderBlock on MI355X (gfx950), bf16 MFMA pipeline.
// B=4 S=2048 D=1024 H=16 DK=64 DFF=4096.
// GEMM BN=256: 2-phase/tile (validated R17).  BN=128: 1-phase (validated R16).
// Attention (R18): 4-warp blocks / 128 q-rows / grid 1024 -> 4 blocks/CU
//       (occupancy was the binding resource: 2 blocks/CU, pipes 90% summed).
//       Same validated softmax machinery (defer-max exp2, lacc via ones-MFMA,
//       XOR swizzle, dbuf VMCNT(0) loop); staging now 4 loads/thread.

#define DI __device__ __forceinline__

typedef __attribute__((ext_vector_type(4))) float f32x4;
typedef __attribute__((ext_vector_type(16))) float f32x16;
typedef __attribute__((ext_vector_type(8))) short bf16x8;
typedef __attribute__((ext_vector_type(4))) short s16x4;

#define B_ 4
#define S_ 2048
#define D_ 1024
#define H_ 16
#define DK_ 64
#define DFF_ 4096
#define M_ 8192

DI float bf2f(short s) {
  union { unsigned u; float f; } v;
  v.u = ((unsigned)(unsigned short)s) << 16;
  return v.f;
}
DI short f2bf(float f) {
  union { float f; unsigned u; } v;
  v.f = f;
  unsigned r = v.u + 0x7FFFu + ((v.u >> 16) & 1u);
  return (short)(r >> 16);
}
DI unsigned pkbf(float lo, float hi) {
  unsigned r;
  asm("v_cvt_pk_bf16_f32 %0, %1, %2" : "=v"(r) : "v"(lo), "v"(hi));
  return r;
}
DI void plswap(unsigned& a, unsigned& b) {
  asm volatile("v_permlane32_swap_b32 %0, %1" : "+v"(a), "+v"(b));
}
DI float ex2(float x) {
  float r;
  asm("v_exp_f32 %0, %1" : "=v"(r) : "v"(x));
  return r;
}
DI float max3(float a, float b, float c) {
  float r;
  asm("v_max3_f32 %0, %1, %2, %3" : "=v"(r) : "v"(a), "v"(b), "v"(c));
  return r;
}

// ---------------- fp32 -> bf16 convert (vectorized) ----------------
__global__ __launch_bounds__(256) void cvt_kernel(const float* __restrict__ in,
                                                  short* __restrict__ out, int n) {
  long i = ((long)blockIdx.x * blockDim.x + threadIdx.x) * 8;
  if (i >= n) return;
  f32x4 a = *(const f32x4*)(in + i);
  f32x4 b = *(const f32x4*)(in + i + 4);
  bf16x8 r;
  r[0] = f2bf(a[0]); r[1] = f2bf(a[1]); r[2] = f2bf(a[2]); r[3] = f2bf(a[3]);
  r[4] = f2bf(b[0]); r[5] = f2bf(b[1]); r[6] = f2bf(b[2]); r[7] = f2bf(b[3]);
  *(bf16x8*)(out + i) = r;
}

DI void gl_lds16(const void* g, void* l) {
  __builtin_amdgcn_global_load_lds(
      (const __attribute__((address_space(1))) unsigned int*)g,
      (__attribute__((address_space(3))) unsigned int*)l, 16, 0, 0);
}

#define VMCNT(N) asm volatile("s_waitcnt vmcnt(" #N ")" ::: "memory")
#define LGKM0                                          \
  asm volatile("s_waitcnt lgkmcnt(0)" ::: "memory");   \
  __builtin_amdgcn_sched_barrier(0)
#define BAR __builtin_amdgcn_s_barrier()
#define PRIO1 __builtin_amdgcn_s_setprio(1)
#define PRIO0 __builtin_amdgcn_s_setprio(0)

// LDS frag read: [128][64]-short half-tile, logical 16B slot s at row r stored
// at physical slot s^(r&7).
DI bf16x8 ldf(const short* base, int row, int kk, int lk) {
  return *(const bf16x8*)(base + row * 64 + (((4 * kk + lk) ^ (row & 7)) << 3));
}

// ---------------- GEMM C = A @ B^T (+bias epilogues) --------------
// MODE 0: bf16 out + bias; MODE 1: + ReLU; MODE 2: QKV scatter (Q scaled
//   log2e/8, Q/K -> [B,H,S,DK], V -> transposed [B,H,DK,S]).  BN in {256,128}.
template <int BN, int MODE>
__global__ __launch_bounds__(512, 2)
void gemm8p(const short* __restrict__ A, const short* __restrict__ Bm,
            const float* __restrict__ bias0, const float* __restrict__ bias1,
            const float* __restrict__ bias2, short* __restrict__ C,
            int M, int N, int K,
            short* __restrict__ Qo, short* __restrict__ Ko, short* __restrict__ Vo) {
  constexpr int BH = BN / 128;             // B half-tiles (2 or 1)
  constexpr int MQ = (BN == 256 ? 4 : 2);  // A frags per quadrant
  constexpr int MF = 2 * MQ;
  constexpr int NFr = 4;
  constexpr int WM = (BN == 256 ? 128 : 64);
  constexpr int WN = 64;

  __shared__ short As[2 * 2 * 8192];
  __shared__ short Bs[2 * BH * 8192];

  const int t = threadIdx.x, w = t >> 6, l = t & 63;
  const int wm = (BN == 256 ? (w >> 2) : (w >> 1));
  const int wn = (BN == 256 ? (w & 3) : (w & 1));
  const int lr = l & 15, lk = l >> 4;
  const int ah = (BN == 256 ? wm : (wm >> 1));       // wave's A half-tile
  const int ab = (BN == 256 ? 0 : (wm & 1) * 64);    // row base within half
  const int bh = (BN == 256 ? (wn >> 1) : 0);        // wave's B half-tile
  const int bb = (BN == 256 ? (wn & 1) * 64 : wn * 64);

  // 2D-rect XCD chunking (gx even, gy%4==0)
  const int gx = gridDim.x, gy = gridDim.y;
  const int orig = blockIdx.y * gx + blockIdx.x;
  const int xcd = orig & 7, k7 = orig >> 3;
  const int rw = gx >> 1, rh = gy >> 2;
  const int row0 = ((xcd >> 1) * rh + k7 / rw) * 256;
  const int col0 = ((xcd & 1) * rw + k7 % rw) * BN;

  const int NT = K >> 6;

  const int rl0 = t >> 3;
  const int csw = ((t & 7) ^ (rl0 & 7)) << 3;
  const short* Abase = A + (long)row0 * K;
  const short* Bbase = Bm + (long)col0 * K;

  auto stA = [&](int b, int kt, int h) {
    short* dst = As + ((b * 2 + h) << 13);
    const short* s = Abase + (long)(h * 128 + rl0) * K + (kt << 6) + csw;
    gl_lds16(s, dst + t * 8);
    gl_lds16(s + (long)64 * K, dst + (t + 512) * 8);
  };
  auto stB = [&](int b, int kt, int h) {
    short* dst = Bs + ((b * BH + h) << 13);
    const short* s = Bbase + (long)(h * 128 + rl0) * K + (kt << 6) + csw;
    gl_lds16(s, dst + t * 8);
    gl_lds16(s + (long)64 * K, dst + (t + 512) * 8);
  };

  f32x4 acc[MF][NFr] = {};

  if constexpr (BN == 256) {
    // prologue: tile0 fully + tile1 minus A-half1 (A1(1) staged at P1 of u=0)
    stA(0, 0, 0); stA(0, 0, 1);
    stB(0, 0, 0); stB(0, 0, 1);
    stB(1, 1, 0); stB(1, 1, 1);
    stA(1, 1, 0);
    VMCNT(6);
    BAR;

    for (int u = 0; u < NT; ++u) {
      const int rb = u & 1, ob = rb ^ 1;
      const short* aw = As + ((rb * 2 + ah) << 13);
      const short* bw = Bs + ((rb * BH + bh) << 13);
      const bool m1 = (u + 1 < NT), m2 = (u + 2 < NT);
      bf16x8 a0[MQ][2], a1[MQ][2], bfv[NFr][2];

      // ---- P1: A-half mh0 x all B ----
#pragma unroll
      for (int m = 0; m < MQ; ++m) {
        const int r = m * 16 + lr;
        a0[m][0] = ldf(aw, r, 0, lk); a0[m][1] = ldf(aw, r, 1, lk);
      }
#pragma unroll
      for (int n = 0; n < NFr; ++n) {
        const int r = bb + n * 16 + lr;
        bfv[n][0] = ldf(bw, r, 0, lk); bfv[n][1] = ldf(bw, r, 1, lk);
      }
      if (m1) stA(ob, u + 1, 1);
      LGKM0; PRIO1;
#pragma unroll
      for (int m = 0; m < MQ; ++m)
#pragma unroll
        for (int n = 0; n < NFr; ++n)
#pragma unroll
          for (int kk = 0; kk < 2; ++kk)
            acc[m][n] = __builtin_amdgcn_mfma_f32_16x16x32_bf16(
                a0[m][kk], bfv[n][kk], acc[m][n], 0, 0, 0);
      PRIO0;

      // ---- P2: A-half mh1 x all B (B reused from registers) ----
#pragma unroll
      for (int m = 0; m < MQ; ++m) {
        const int r = 64 + m * 16 + lr;
        a1[m][0] = ldf(aw, r, 0, lk); a1[m][1] = ldf(aw, r, 1, lk);
      }
      LGKM0;
      BAR;  // all waves' reads of buffer rb complete -> overwrite is safe
      if (m2) { stB(rb, u + 2, 0); stB(rb, u + 2, 1); stA(rb, u + 2, 0); }
      PRIO1;
#pragma unroll
      for (int m = 0; m < MQ; ++m)
#pragma unroll
        for (int n = 0; n < NFr; ++n)
#pragma unroll
          for (int kk = 0; kk < 2; ++kk)
            acc[MQ + m][n] = __builtin_amdgcn_mfma_f32_16x16x32_bf16(
                a1[m][kk], bfv[n][kk], acc[MQ + m][n], 0, 0, 0);
      PRIO0;
      // counted vmcnt BEFORE the closing barrier (tile u+1 fully landed)
      if (m2) { VMCNT(6); } else { VMCNT(0); }
      BAR;
    }
  } else {
    // ---- BN=128: single-phase/tile (validated R16) ----
    stA(0, 0, 0); stA(0, 0, 1); stB(0, 0, 0);
    stA(1, 1, 0); stA(1, 1, 1); stB(1, 1, 0);
    VMCNT(6);  // tile 0 landed; tile 1 in flight
    BAR;

    for (int u = 0; u < NT; ++u) {
      const int rb = u & 1;
      const short* aw = As + ((rb * 2 + ah) << 13);
      const short* bw = Bs + (rb << 13);
      const bool m2 = (u + 2 < NT);
      bf16x8 af[4][2], bfv[4][2];
#pragma unroll
      for (int m = 0; m < 4; ++m) {
        const int r = ab + m * 16 + lr;
        af[m][0] = ldf(aw, r, 0, lk); af[m][1] = ldf(aw, r, 1, lk);
      }
#pragma unroll
      for (int n = 0; n < 4; ++n) {
        const int r = bb + n * 16 + lr;
        bfv[n][0] = ldf(bw, r, 0, lk); bfv[n][1] = ldf(bw, r, 1, lk);
      }
      BAR;  // all waves' reads are queued; staged writes land >=200cy later
      if (m2) { stA(rb, u + 2, 0); stA(rb, u + 2, 1); stB(rb, u + 2, 0); }
      LGKM0;
      PRIO1;
#pragma unroll
      for (int m = 0; m < 4; ++m)
#pragma unroll
        for (int n = 0; n < 4; ++n)
#pragma unroll
          for (int kk = 0; kk < 2; ++kk)
            acc[m][n] = __builtin_amdgcn_mfma_f32_16x16x32_bf16(
                af[m][kk], bfv[n][kk], acc[m][n], 0, 0, 0);
      PRIO0;
      if (m2) { VMCNT(6); } else { VMCNT(0); }
      BAR;
    }
  }

  // epilogue: C/D layout col = lane&15, row = (lane>>4)*4 + j
  if (MODE == 2) {
    const int which = col0 >> 10;  // uniform per block
#pragma unroll
    for (int m = 0; m < MF; ++m) {
#pragma unroll
      for (int n = 0; n < NFr; ++n) {
        const int r0e = row0 + wm * WM + m * 16 + lk * 4;
        const int c = col0 + wn * WN + n * 16 + lr;
        const int cc = c & 1023;
        const int h = cc >> 6, dk = cc & 63;
        const int bbx = r0e >> 11, s = r0e & 2047;
        if (which == 2) {
          const float bias = bias2[cc];
          s16x4 v4;
#pragma unroll
          for (int j = 0; j < 4; ++j) v4[j] = f2bf(acc[m][n][j] + bias);
          *(s16x4*)(Vo + ((long)((bbx * H_ + h) * DK_ + dk)) * S_ + s) = v4;
        } else {
          const float bias = (which == 0 ? bias0[cc] : bias1[cc]);
          const float sc = (which == 0 ? 0.1803368801f : 1.0f);  // log2e/8
          short* dst = (which == 0 ? Qo : Ko);
#pragma unroll
          for (int j = 0; j < 4; ++j)
            dst[(((long)(bbx * H_ + h) * S_) + s + j) * DK_ + dk] =
                f2bf((acc[m][n][j] + bias) * sc);
        }
      }
    }
  } else {
#pragma unroll
    for (int m = 0; m < MF; ++m) {
#pragma unroll
      for (int n = 0; n < NFr; ++n) {
#pragma unroll
        for (int j = 0; j < 4; ++j) {
          const int r = row0 + wm * WM + m * 16 + lk * 4 + j;
          const int c = col0 + wn * WN + n * 16 + lr;
          float v = acc[m][n][j] + bias0[c];
          if (MODE == 1) v = fmaxf(v, 0.0f);
          C[(long)r * N + c] = f2bf(v);
        }
      }
    }
  }
}

// ---------------- Flash attention, 4-warp swapped-QK^T 32x32 ----------------
// 4 warps x 32 q-rows = 128 q/block; grid 1024 -> 4 blocks/CU.  KV tile 64,
// double-buffered; staging 4 loads/thread right after loop-top barrier.
// bh-grouped XCD remap.  exp2 softmax (Q prescaled log2e/8), defer-max THR=8.
// Row-sum via MFMA with all-ones A-frag.
__global__ __launch_bounds__(256, 4)
void attn_kernel(const short* __restrict__ Q, const short* __restrict__ K,
                 const short* __restrict__ Vt, short* __restrict__ ctx) {
  __shared__ short Ks[2 * 4096];
  __shared__ short Vs[2 * 4096];
  const int t = threadIdx.x, w = t >> 6, l = t & 63;
  const int q31 = l & 31, hi = l >> 5;

  // bh-grouped XCD remap (gridDim.x=16 q-tiles, gridDim.y=64 bh)
  const int orig = blockIdx.y * gridDim.x + blockIdx.x;
  const int xcd = orig & 7, k7 = orig >> 3;
  const int bh = xcd * 8 + (k7 >> 4);
  const int q0 = (k7 & 15) * 128 + w * 32;
  const long base = (long)bh * S_ * DK_;

  bf16x8 qf[4];
  {
    const short* qp = Q + base + (long)(q0 + q31) * DK_ + hi * 8;
#pragma unroll
    for (int ks = 0; ks < 4; ++ks) qf[ks] = *(const bf16x8*)(qp + ks * 16);
  }

  bf16x8 ones;
#pragma unroll
  for (int i = 0; i < 8; ++i) ones[i] = (short)0x3F80;  // bf16 1.0

  f32x16 oa[2] = {};
  f32x16 lacc = {};           // all 16 elements = running row sum
  float mrun = -1e30f;

  // staging: thread t covers chunks t and t+256 of the 64x64 tile
  const int trow = t >> 3;                         // rows trow and trow+32
  const int tcol = (((t & 7) ^ (trow & 7)) << 3);  // swizzled source col
  const int tcol2 = (((t & 7) ^ ((trow + 32) & 7)) << 3);
  const short* Ksrc0 = K + base + (long)trow * DK_ + tcol;
  const short* Ksrc1 = K + base + (long)(trow + 32) * DK_ + tcol2;
  const short* Vsrc0 = Vt + base + (long)trow * S_ + tcol;
  const short* Vsrc1 = Vt + base + (long)(trow + 32) * S_ + tcol2;

  auto stg = [&](int tile, int slot) {
    const int kb = slot * 4096;
    const int kvn = tile * 64;
    gl_lds16(Ksrc0 + (long)kvn * DK_, &Ks[kb + t * 8]);
    gl_lds16(Ksrc1 + (long)kvn * DK_, &Ks[kb + (t + 256) * 8]);
    gl_lds16(Vsrc0 + kvn, &Vs[kb + t * 8]);
    gl_lds16(Vsrc1 + kvn, &Vs[kb + (t + 256) * 8]);
  };

  stg(0, 0);

  for (int tt = 0; tt < 32; ++tt) {
    VMCNT(0);
    BAR;
    if (tt + 1 < 32) stg(tt + 1, (tt + 1) & 1);
    const int cb = (tt & 1) * 4096;

    // S^T = K x Q (log2 domain): D[kv][q], col=q=l&31
    f32x16 sacc[2] = {};
#pragma unroll
    for (int m = 0; m < 2; ++m) {
      const int row = m * 32 + q31;
      const int sw = row & 7;
#pragma unroll
      for (int ks = 0; ks < 4; ++ks) {
        bf16x8 kf = *(const bf16x8*)&Ks[cb + row * 64 + (((2 * ks + hi) ^ sw) << 3)];
        sacc[m] = __builtin_amdgcn_mfma_f32_32x32x16_bf16(kf, qf[ks], sacc[m], 0, 0, 0);
      }
    }

    // max tree via v_max3 + shfl cross-half
    float mx[8];
#pragma unroll
    for (int r = 0; r < 8; ++r)
      mx[r] = fmaxf(max3(sacc[0][r], sacc[0][r + 8], sacc[1][r]), sacc[1][r + 8]);
    float ma = max3(mx[0], mx[1], mx[2]);
    float mb = max3(mx[3], mx[4], mx[5]);
    float tm = fmaxf(max3(mx[6], mx[7], ma), mb);
    tm = fmaxf(tm, __shfl_xor(tm, 32, 64));

    // T13 defer-max: rescale only when max grew by > 8 (log2 units)
    if (!__all(tm <= mrun + 8.0f)) {
      const float mnew = fmaxf(mrun, tm);
      const float fac = ex2(mrun - mnew);
#pragma unroll
      for (int r = 0; r < 16; ++r) lacc[r] *= fac;
#pragma unroll
      for (int m = 0; m < 2; ++m)
#pragma unroll
        for (int r = 0; r < 16; ++r) oa[m][r] *= fac;
      mrun = mnew;
    }

#pragma unroll
    for (int m = 0; m < 2; ++m)
#pragma unroll
      for (int r = 0; r < 16; ++r) sacc[m][r] = ex2(sacc[m][r] - mrun);

    // P -> bf16 B-frags via cvt_pk + permlane32_swap
    bf16x8 pf[4];
#pragma unroll
    for (int m = 0; m < 2; ++m)
#pragma unroll
      for (int sb = 0; sb < 2; ++sb) {
        unsigned p0 = pkbf(sacc[m][8 * sb + 0], sacc[m][8 * sb + 1]);
        unsigned p1 = pkbf(sacc[m][8 * sb + 2], sacc[m][8 * sb + 3]);
        unsigned p2 = pkbf(sacc[m][8 * sb + 4], sacc[m][8 * sb + 5]);
        unsigned p3 = pkbf(sacc[m][8 * sb + 6], sacc[m][8 * sb + 7]);
        plswap(p0, p2);
        plswap(p1, p3);
        union { unsigned u[4]; bf16x8 v; } fb;
        fb.u[0] = p0; fb.u[1] = p1; fb.u[2] = p2; fb.u[3] = p3;
        pf[2 * m + sb] = fb.v;
      }

    // O^T += V^T x P ; row-sum += ones x P (spans all 64 kv -> no shfl)
#pragma unroll
    for (int s = 0; s < 4; ++s) {
      lacc = __builtin_amdgcn_mfma_f32_32x32x16_bf16(ones, pf[s], lacc, 0, 0, 0);
#pragma unroll
      for (int mt = 0; mt < 2; ++mt) {
        const int row = mt * 32 + q31;
        const int sw = row & 7;
        bf16x8 vf = *(const bf16x8*)&Vs[cb + row * 64 + (((2 * s + hi) ^ sw) << 3)];
        oa[mt] = __builtin_amdgcn_mfma_f32_32x32x16_bf16(vf, pf[s], oa[mt], 0, 0, 0);
      }
    }
  }

  // epilogue: ctx[b, s=q0+q31, h*64+dk]
  const int bb2 = bh >> 4, h = bh & 15;
  const float rl = 1.0f / lacc[0];
  short* crow = ctx + ((long)(bb2 * S_ + q0 + q31)) * D_ + h * 64 + 4 * hi;
#pragma unroll
  for (int mt = 0; mt < 2; ++mt)
#pragma unroll
    for (int g = 0; g < 4; ++g) {
      s16x4 v4;
#pragma unroll
      for (int i = 0; i < 4; ++i) v4[i] = f2bf(oa[mt][4 * g + i] * rl);
      *(s16x4*)(crow + mt * 32 + g * 8) = v4;
    }
}

// ---------------- out = residual + LayerNorm(a) ----------------
template <int RES_BF16, int OUT_BF16>
__global__ __launch_bounds__(256)
void add_ln(const void* __restrict__ resv, const short* __restrict__ a,
            const float* __restrict__ gam, const float* __restrict__ bet,
            void* __restrict__ outv) {
  const int row = blockIdx.x, t = threadIdx.x;
  const int w = t >> 6, l = t & 63;
  const long roff = (long)row * D_;
  const int c = t * 4;
  s16x4 av = *(const s16x4*)(a + roff + c);
  float v0 = bf2f(av[0]), v1 = bf2f(av[1]), v2 = bf2f(av[2]), v3 = bf2f(av[3]);
  float s = v0 + v1 + v2 + v3;
#pragma unroll
  for (int mask = 1; mask < 64; mask <<= 1) s += __shfl_xor(s, mask, 64);
  __shared__ float r1[4], r2[4];
  if (l == 0) r1[w] = s;
  __syncthreads();
  float mu = (r1[0] + r1[1] + r1[2] + r1[3]) * (1.0f / D_);
  float d0 = v0 - mu, d1 = v1 - mu, d2 = v2 - mu, d3 = v3 - mu;
  float sq = d0 * d0 + d1 * d1 + d2 * d2 + d3 * d3;
#pragma unroll
  for (int mask = 1; mask < 64; mask <<= 1) sq += __shfl_xor(sq, mask, 64);
  if (l == 0) r2[w] = sq;
  __syncthreads();
  float var = (r2[0] + r2[1] + r2[2] + r2[3]) * (1.0f / D_);
  float rs = rsqrtf(var + 1e-5f);
  float res0, res1, res2, res3;
  if (RES_BF16) {
    s16x4 rv = *(const s16x4*)((const short*)resv + roff + c);
    res0 = bf2f(rv[0]); res1 = bf2f(rv[1]); res2 = bf2f(rv[2]); res3 = bf2f(rv[3]);
  } else {
    f32x4 rv = *(const f32x4*)((const float*)resv + roff + c);
    res0 = rv[0]; res1 = rv[1]; res2 = rv[2]; res3 = rv[3];
  }
  float o0 = res0 + d0 * rs * gam[c + 0] + bet[c + 0];
  float o1 = res1 + d1 * rs * gam[c + 1] + bet[c + 1];
  float o2 = res2 + d2 * rs * gam[c + 2] + bet[c + 2];
  float o3 = res3 + d3 * rs * gam[c + 3] + bet[c + 3];
  if (OUT_BF16) {
    s16x4 ov;
    ov[0] = f2bf(o0); ov[1] = f2bf(o1); ov[2] = f2bf(o2); ov[3] = f2bf(o3);
    *(s16x4*)((short*)outv + roff + c) = ov;
  } else {
    f32x4 ov;
    ov[0] = o0; ov[1] = o1; ov[2] = o2; ov[3] = o3;
    *(f32x4*)((float*)outv + roff + c) = ov;
  }
}

extern "C" void kernel_launch(void* const* d_in, const int* in_sizes, int n_in,
                              void* d_out, int out_size, void* d_ws, size_t ws_size,
                              hipStream_t stream) {
  (void)in_sizes; (void)n_in; (void)out_size; (void)ws_size;
  const float* x   = (const float*)d_in[0];
  const float* wq  = (const float*)d_in[1];
  const float* bq  = (const float*)d_in[2];
  const float* wk  = (const float*)d_in[3];
  const float* bk  = (const float*)d_in[4];
  const float* wv  = (const float*)d_in[5];
  const float* bv  = (const float*)d_in[6];
  const float* wo  = (const float*)d_in[7];
  const float* bo  = (const float*)d_in[8];
  const float* w1  = (const float*)d_in[9];
  const float* b1  = (const float*)d_in[10];
  const float* w2  = (const float*)d_in[11];
  const float* b2  = (const float*)d_in[12];
  const float* g1  = (const float*)d_in[13];
  const float* be1 = (const float*)d_in[14];
  const float* g2  = (const float*)d_in[15];
  const float* be2 = (const float*)d_in[16];

  char* ws = (char*)d_ws;
  const long MB = 1 << 20;
  short* xb    = (short*)(ws + 0 * MB);
  short* wqkvb = (short*)(ws + 16 * MB);
  short* wob   = (short*)(ws + 22 * MB);
  short* w1b   = (short*)(ws + 24 * MB);
  short* w2b   = (short*)(ws + 32 * MB);
  short* Qb    = (short*)(ws + 40 * MB);
  short* Kb    = (short*)(ws + 56 * MB);
  short* Vtb   = (short*)(ws + 72 * MB);   // V transposed [B,H,DK,S]
  short* ctxb  = (short*)(ws + 88 * MB);
  short* aout  = (short*)(ws + 40 * MB);   // reuse Q
  short* x1b   = (short*)(ws + 56 * MB);   // reuse K
  short* hid   = (short*)(ws + 88 * MB);   // reuse ctx (64MB, [88,152))
  short* ffb   = (short*)(ws + 72 * MB);   // reuse Vt

  auto cvt = [&](const float* in, short* out, long n) {
    cvt_kernel<<<dim3((unsigned)((n / 8 + 255) / 256)), dim3(256), 0, stream>>>(in, out, (int)n);
  };
  cvt(x, xb, (long)M_ * D_);
  cvt(wq, wqkvb + 0L * D_ * D_, (long)D_ * D_);
  cvt(wk, wqkvb + 1L * D_ * D_, (long)D_ * D_);
  cvt(wv, wqkvb + 2L * D_ * D_, (long)D_ * D_);
  cvt(wo, wob, (long)D_ * D_);
  cvt(w1, w1b, (long)DFF_ * D_);
  cvt(w2, w2b, (long)D_ * DFF_);

  // QKV projection (fused, N=3072): Q scaled log2e/8, V written transposed
  gemm8p<256, 2><<<dim3(3072 / 256, M_ / 256), 512, 0, stream>>>(
      xb, wqkvb, bq, bk, bv, nullptr, M_, 3072, D_, Qb, Kb, Vtb);

  attn_kernel<<<dim3(S_ / 128, B_ * H_), 256, 0, stream>>>(Qb, Kb, Vtb, ctxb);

  // O projection (N=1024 -> BN=128, grid = 256 blocks)
  gemm8p<128, 0><<<dim3(D_ / 128, M_ / 256), 512, 0, stream>>>(
      ctxb, wob, bo, nullptr, nullptr, aout, M_, D_, D_, nullptr, nullptr, nullptr);

  // x1 = x + LN(attn_out)
  add_ln<0, 1><<<dim3(M_), 256, 0, stream>>>(x, aout, g1, be1, x1b);

  // FFN
  gemm8p<256, 1><<<dim3(DFF_ / 256, M_ / 256), 512, 0, stream>>>(
      x1b, w1b, b1, nullptr, nullptr, hid, M_, DFF_, D_, nullptr, nullptr, nullptr);
  gemm8p<128, 0><<<dim3(D_ / 128, M_ / 256), 512, 0, stream>>>(
      hid, w2b, b2, nullptr, nullptr, ffb, M_, D_, DFF_, nullptr, nullptr, nullptr);

  // out = x1 + LN(ff)
  add_ln<1, 0><<<dim3(M_), 256, 0, stream>>>(x1b, ffb, g2, be2, d_out);
}

// Round 19
// 375.857 us; speedup vs baseline: 1.0153x; 1.0153x over previous
//
#include <hip/hip_runtime.h>
#include <hip/hip_bf16.h>
#include <stdint.h>

// EncoderBlock on MI355X (gfx950), bf16 MFMA pipeline.   FINAL (== R17 best)
// B=4 S=2048 D=1024 H=16 DK=64 DFF=4096.
// GEMM BN=256: 2-phase/tile, BK=64, 8 waves, dbuf LDS, staggered staging,
//       counted vmcnt(6), B-frag register reuse, row&7 XOR swizzle, setprio,
//       2D-rect XCD chunking.  (validated R17)
// GEMM BN=128: single-phase/tile.  (validated R16)
// Attention: 8-warp swapped-QK^T 32x32, dbuf K/V, bh-grouped XCD remap,
//       exp2 softmax + defer-max + max3 tree, row-sum via all-ones MFMA.
//       (validated R11/R12/R15/R16/R17; 4-warp variant regressed R18)

#define DI __device__ __forceinline__

typedef __attribute__((ext_vector_type(4))) float f32x4;
typedef __attribute__((ext_vector_type(16))) float f32x16;
typedef __attribute__((ext_vector_type(8))) short bf16x8;
typedef __attribute__((ext_vector_type(4))) short s16x4;

#define B_ 4
#define S_ 2048
#define D_ 1024
#define H_ 16
#define DK_ 64
#define DFF_ 4096
#define M_ 8192

DI float bf2f(short s) {
  union { unsigned u; float f; } v;
  v.u = ((unsigned)(unsigned short)s) << 16;
  return v.f;
}
DI short f2bf(float f) {
  union { float f; unsigned u; } v;
  v.f = f;
  unsigned r = v.u + 0x7FFFu + ((v.u >> 16) & 1u);
  return (short)(r >> 16);
}
DI unsigned pkbf(float lo, float hi) {
  unsigned r;
  asm("v_cvt_pk_bf16_f32 %0, %1, %2" : "=v"(r) : "v"(lo), "v"(hi));
  return r;
}
DI void plswap(unsigned& a, unsigned& b) {
  asm volatile("v_permlane32_swap_b32 %0, %1" : "+v"(a), "+v"(b));
}
DI float ex2(float x) {
  float r;
  asm("v_exp_f32 %0, %1" : "=v"(r) : "v"(x));
  return r;
}
DI float max3(float a, float b, float c) {
  float r;
  asm("v_max3_f32 %0, %1, %2, %3" : "=v"(r) : "v"(a), "v"(b), "v"(c));
  return r;
}

// ---------------- fp32 -> bf16 convert (vectorized) ----------------
__global__ __launch_bounds__(256) void cvt_kernel(const float* __restrict__ in,
                                                  short* __restrict__ out, int n) {
  long i = ((long)blockIdx.x * blockDim.x + threadIdx.x) * 8;
  if (i >= n) return;
  f32x4 a = *(const f32x4*)(in + i);
  f32x4 b = *(const f32x4*)(in + i + 4);
  bf16x8 r;
  r[0] = f2bf(a[0]); r[1] = f2bf(a[1]); r[2] = f2bf(a[2]); r[3] = f2bf(a[3]);
  r[4] = f2bf(b[0]); r[5] = f2bf(b[1]); r[6] = f2bf(b[2]); r[7] = f2bf(b[3]);
  *(bf16x8*)(out + i) = r;
}

DI void gl_lds16(const void* g, void* l) {
  __builtin_amdgcn_global_load_lds(
      (const __attribute__((address_space(1))) unsigned int*)g,
      (__attribute__((address_space(3))) unsigned int*)l, 16, 0, 0);
}

#define VMCNT(N) asm volatile("s_waitcnt vmcnt(" #N ")" ::: "memory")
#define LGKM0                                          \
  asm volatile("s_waitcnt lgkmcnt(0)" ::: "memory");   \
  __builtin_amdgcn_sched_barrier(0)
#define BAR __builtin_amdgcn_s_barrier()
#define PRIO1 __builtin_amdgcn_s_setprio(1)
#define PRIO0 __builtin_amdgcn_s_setprio(0)

// LDS frag read: [128][64]-short half-tile, logical 16B slot s at row r stored
// at physical slot s^(r&7).
DI bf16x8 ldf(const short* base, int row, int kk, int lk) {
  return *(const bf16x8*)(base + row * 64 + (((4 * kk + lk) ^ (row & 7)) << 3));
}

// ---------------- GEMM C = A @ B^T (+bias epilogues) --------------
// MODE 0: bf16 out + bias; MODE 1: + ReLU; MODE 2: QKV scatter (Q scaled
//   log2e/8, Q/K -> [B,H,S,DK], V -> transposed [B,H,DK,S]).  BN in {256,128}.
template <int BN, int MODE>
__global__ __launch_bounds__(512, 2)
void gemm8p(const short* __restrict__ A, const short* __restrict__ Bm,
            const float* __restrict__ bias0, const float* __restrict__ bias1,
            const float* __restrict__ bias2, short* __restrict__ C,
            int M, int N, int K,
            short* __restrict__ Qo, short* __restrict__ Ko, short* __restrict__ Vo) {
  constexpr int BH = BN / 128;             // B half-tiles (2 or 1)
  constexpr int MQ = (BN == 256 ? 4 : 2);  // A frags per quadrant
  constexpr int MF = 2 * MQ;
  constexpr int NFr = 4;
  constexpr int WM = (BN == 256 ? 128 : 64);
  constexpr int WN = 64;

  __shared__ short As[2 * 2 * 8192];
  __shared__ short Bs[2 * BH * 8192];

  const int t = threadIdx.x, w = t >> 6, l = t & 63;
  const int wm = (BN == 256 ? (w >> 2) : (w >> 1));
  const int wn = (BN == 256 ? (w & 3) : (w & 1));
  const int lr = l & 15, lk = l >> 4;
  const int ah = (BN == 256 ? wm : (wm >> 1));       // wave's A half-tile
  const int ab = (BN == 256 ? 0 : (wm & 1) * 64);    // row base within half
  const int bh = (BN == 256 ? (wn >> 1) : 0);        // wave's B half-tile
  const int bb = (BN == 256 ? (wn & 1) * 64 : wn * 64);

  // 2D-rect XCD chunking (gx even, gy%4==0)
  const int gx = gridDim.x, gy = gridDim.y;
  const int orig = blockIdx.y * gx + blockIdx.x;
  const int xcd = orig & 7, k7 = orig >> 3;
  const int rw = gx >> 1, rh = gy >> 2;
  const int row0 = ((xcd >> 1) * rh + k7 / rw) * 256;
  const int col0 = ((xcd & 1) * rw + k7 % rw) * BN;

  const int NT = K >> 6;

  const int rl0 = t >> 3;
  const int csw = ((t & 7) ^ (rl0 & 7)) << 3;
  const short* Abase = A + (long)row0 * K;
  const short* Bbase = Bm + (long)col0 * K;

  auto stA = [&](int b, int kt, int h) {
    short* dst = As + ((b * 2 + h) << 13);
    const short* s = Abase + (long)(h * 128 + rl0) * K + (kt << 6) + csw;
    gl_lds16(s, dst + t * 8);
    gl_lds16(s + (long)64 * K, dst + (t + 512) * 8);
  };
  auto stB = [&](int b, int kt, int h) {
    short* dst = Bs + ((b * BH + h) << 13);
    const short* s = Bbase + (long)(h * 128 + rl0) * K + (kt << 6) + csw;
    gl_lds16(s, dst + t * 8);
    gl_lds16(s + (long)64 * K, dst + (t + 512) * 8);
  };

  f32x4 acc[MF][NFr] = {};

  if constexpr (BN == 256) {
    // prologue: tile0 fully + tile1 minus A-half1 (A1(1) staged at P1 of u=0)
    stA(0, 0, 0); stA(0, 0, 1);
    stB(0, 0, 0); stB(0, 0, 1);
    stB(1, 1, 0); stB(1, 1, 1);
    stA(1, 1, 0);
    VMCNT(6);
    BAR;

    for (int u = 0; u < NT; ++u) {
      const int rb = u & 1, ob = rb ^ 1;
      const short* aw = As + ((rb * 2 + ah) << 13);
      const short* bw = Bs + ((rb * BH + bh) << 13);
      const bool m1 = (u + 1 < NT), m2 = (u + 2 < NT);
      bf16x8 a0[MQ][2], a1[MQ][2], bfv[NFr][2];

      // ---- P1: A-half mh0 x all B ----
#pragma unroll
      for (int m = 0; m < MQ; ++m) {
        const int r = m * 16 + lr;
        a0[m][0] = ldf(aw, r, 0, lk); a0[m][1] = ldf(aw, r, 1, lk);
      }
#pragma unroll
      for (int n = 0; n < NFr; ++n) {
        const int r = bb + n * 16 + lr;
        bfv[n][0] = ldf(bw, r, 0, lk); bfv[n][1] = ldf(bw, r, 1, lk);
      }
      if (m1) stA(ob, u + 1, 1);
      LGKM0; PRIO1;
#pragma unroll
      for (int m = 0; m < MQ; ++m)
#pragma unroll
        for (int n = 0; n < NFr; ++n)
#pragma unroll
          for (int kk = 0; kk < 2; ++kk)
            acc[m][n] = __builtin_amdgcn_mfma_f32_16x16x32_bf16(
                a0[m][kk], bfv[n][kk], acc[m][n], 0, 0, 0);
      PRIO0;

      // ---- P2: A-half mh1 x all B (B reused from registers) ----
#pragma unroll
      for (int m = 0; m < MQ; ++m) {
        const int r = 64 + m * 16 + lr;
        a1[m][0] = ldf(aw, r, 0, lk); a1[m][1] = ldf(aw, r, 1, lk);
      }
      LGKM0;
      BAR;  // all waves' reads of buffer rb complete -> overwrite is safe
      if (m2) { stB(rb, u + 2, 0); stB(rb, u + 2, 1); stA(rb, u + 2, 0); }
      PRIO1;
#pragma unroll
      for (int m = 0; m < MQ; ++m)
#pragma unroll
        for (int n = 0; n < NFr; ++n)
#pragma unroll
          for (int kk = 0; kk < 2; ++kk)
            acc[MQ + m][n] = __builtin_amdgcn_mfma_f32_16x16x32_bf16(
                a1[m][kk], bfv[n][kk], acc[MQ + m][n], 0, 0, 0);
      PRIO0;
      // counted vmcnt BEFORE the closing barrier (tile u+1 fully landed)
      if (m2) { VMCNT(6); } else { VMCNT(0); }
      BAR;
    }
  } else {
    // ---- BN=128: single-phase/tile (validated R16) ----
    stA(0, 0, 0); stA(0, 0, 1); stB(0, 0, 0);
    stA(1, 1, 0); stA(1, 1, 1); stB(1, 1, 0);
    VMCNT(6);  // tile 0 landed; tile 1 in flight
    BAR;

    for (int u = 0; u < NT; ++u) {
      const int rb = u & 1;
      const short* aw = As + ((rb * 2 + ah) << 13);
      const short* bw = Bs + (rb << 13);
      const bool m2 = (u + 2 < NT);
      bf16x8 af[4][2], bfv[4][2];
#pragma unroll
      for (int m = 0; m < 4; ++m) {
        const int r = ab + m * 16 + lr;
        af[m][0] = ldf(aw, r, 0, lk); af[m][1] = ldf(aw, r, 1, lk);
      }
#pragma unroll
      for (int n = 0; n < 4; ++n) {
        const int r = bb + n * 16 + lr;
        bfv[n][0] = ldf(bw, r, 0, lk); bfv[n][1] = ldf(bw, r, 1, lk);
      }
      BAR;  // all waves' reads are queued; staged writes land >=200cy later
      if (m2) { stA(rb, u + 2, 0); stA(rb, u + 2, 1); stB(rb, u + 2, 0); }
      LGKM0;
      PRIO1;
#pragma unroll
      for (int m = 0; m < 4; ++m)
#pragma unroll
        for (int n = 0; n < 4; ++n)
#pragma unroll
          for (int kk = 0; kk < 2; ++kk)
            acc[m][n] = __builtin_amdgcn_mfma_f32_16x16x32_bf16(
                af[m][kk], bfv[n][kk], acc[m][n], 0, 0, 0);
      PRIO0;
      if (m2) { VMCNT(6); } else { VMCNT(0); }
      BAR;
    }
  }

  // epilogue: C/D layout col = lane&15, row = (lane>>4)*4 + j
  if (MODE == 2) {
    const int which = col0 >> 10;  // uniform per block
#pragma unroll
    for (int m = 0; m < MF; ++m) {
#pragma unroll
      for (int n = 0; n < NFr; ++n) {
        const int r0e = row0 + wm * WM + m * 16 + lk * 4;
        const int c = col0 + wn * WN + n * 16 + lr;
        const int cc = c & 1023;
        const int h = cc >> 6, dk = cc & 63;
        const int bbx = r0e >> 11, s = r0e & 2047;
        if (which == 2) {
          const float bias = bias2[cc];
          s16x4 v4;
#pragma unroll
          for (int j = 0; j < 4; ++j) v4[j] = f2bf(acc[m][n][j] + bias);
          *(s16x4*)(Vo + ((long)((bbx * H_ + h) * DK_ + dk)) * S_ + s) = v4;
        } else {
          const float bias = (which == 0 ? bias0[cc] : bias1[cc]);
          const float sc = (which == 0 ? 0.1803368801f : 1.0f);  // log2e/8
          short* dst = (which == 0 ? Qo : Ko);
#pragma unroll
          for (int j = 0; j < 4; ++j)
            dst[(((long)(bbx * H_ + h) * S_) + s + j) * DK_ + dk] =
                f2bf((acc[m][n][j] + bias) * sc);
        }
      }
    }
  } else {
#pragma unroll
    for (int m = 0; m < MF; ++m) {
#pragma unroll
      for (int n = 0; n < NFr; ++n) {
#pragma unroll
        for (int j = 0; j < 4; ++j) {
          const int r = row0 + wm * WM + m * 16 + lk * 4 + j;
          const int c = col0 + wn * WN + n * 16 + lr;
          float v = acc[m][n][j] + bias0[c];
          if (MODE == 1) v = fmaxf(v, 0.0f);
          C[(long)r * N + c] = f2bf(v);
        }
      }
    }
  }
}

// ---------------- Flash attention, 8-warp swapped-QK^T 32x32 ----------------
// 8 warps x 32 q-rows = 256 q/block.  KV tile 64, double-buffered; staging
// issued right after loop-top barrier (1 K-load + 1 V-load per thread).
// bh-grouped XCD remap.  exp2 softmax (Q prescaled log2e/8), defer-max THR=8.
// Row-sum via MFMA with all-ones A-frag (no sum tree, no cross-half sum shfl).
__global__ __launch_bounds__(512, 4)
void attn_kernel(const short* __restrict__ Q, const short* __restrict__ K,
                 const short* __restrict__ Vt, short* __restrict__ ctx) {
  __shared__ short Ks[2 * 4096];
  __shared__ short Vs[2 * 4096];
  const int t = threadIdx.x, w = t >> 6, l = t & 63;
  const int q31 = l & 31, hi = l >> 5;

  // bh-grouped XCD remap (gridDim.x=8 q-tiles, gridDim.y=64 bh)
  const int orig = blockIdx.y * gridDim.x + blockIdx.x;
  const int xcd = orig & 7, k7 = orig >> 3;
  const int bh = xcd * 8 + (k7 >> 3);
  const int q0 = (k7 & 7) * 256 + w * 32;
  const long base = (long)bh * S_ * DK_;

  bf16x8 qf[4];
  {
    const short* qp = Q + base + (long)(q0 + q31) * DK_ + hi * 8;
#pragma unroll
    for (int ks = 0; ks < 4; ++ks) qf[ks] = *(const bf16x8*)(qp + ks * 16);
  }

  bf16x8 ones;
#pragma unroll
  for (int i = 0; i < 8; ++i) ones[i] = (short)0x3F80;  // bf16 1.0

  f32x16 oa[2] = {};
  f32x16 lacc = {};           // all 16 elements = running row sum
  float mrun = -1e30f;

  // staging: thread t covers chunk t of the 64x64 tile (512 chunks of 16B)
  const int trow = t >> 3;                         // K: kv row / V: dk row
  const int tcol = (((t & 7) ^ (trow & 7)) << 3);  // swizzled source col
  const short* Ksrc = K + base + (long)trow * DK_ + tcol;
  const short* Vsrc = Vt + base + (long)trow * S_ + tcol;

  auto stg = [&](int tile, int slot) {
    const int kb = slot * 4096;
    const int kvn = tile * 64;
    gl_lds16(Ksrc + (long)kvn * DK_, &Ks[kb + t * 8]);
    gl_lds16(Vsrc + kvn, &Vs[kb + t * 8]);
  };

  stg(0, 0);

  for (int tt = 0; tt < 32; ++tt) {
    VMCNT(0);
    BAR;
    if (tt + 1 < 32) stg(tt + 1, (tt + 1) & 1);
    const int cb = (tt & 1) * 4096;

    // S^T = K x Q (log2 domain): D[kv][q], col=q=l&31
    f32x16 sacc[2] = {};
#pragma unroll
    for (int m = 0; m < 2; ++m) {
      const int row = m * 32 + q31;
      const int sw = row & 7;
#pragma unroll
      for (int ks = 0; ks < 4; ++ks) {
        bf16x8 kf = *(const bf16x8*)&Ks[cb + row * 64 + (((2 * ks + hi) ^ sw) << 3)];
        sacc[m] = __builtin_amdgcn_mfma_f32_32x32x16_bf16(kf, qf[ks], sacc[m], 0, 0, 0);
      }
    }

    // max tree via v_max3 + shfl cross-half
    float mx[8];
#pragma unroll
    for (int r = 0; r < 8; ++r)
      mx[r] = fmaxf(max3(sacc[0][r], sacc[0][r + 8], sacc[1][r]), sacc[1][r + 8]);
    float ma = max3(mx[0], mx[1], mx[2]);
    float mb = max3(mx[3], mx[4], mx[5]);
    float tm = fmaxf(max3(mx[6], mx[7], ma), mb);
    tm = fmaxf(tm, __shfl_xor(tm, 32, 64));

    // T13 defer-max: rescale only when max grew by > 8 (log2 units)
    if (!__all(tm <= mrun + 8.0f)) {
      const float mnew = fmaxf(mrun, tm);
      const float fac = ex2(mrun - mnew);
#pragma unroll
      for (int r = 0; r < 16; ++r) lacc[r] *= fac;
#pragma unroll
      for (int m = 0; m < 2; ++m)
#pragma unroll
        for (int r = 0; r < 16; ++r) oa[m][r] *= fac;
      mrun = mnew;
    }

#pragma unroll
    for (int m = 0; m < 2; ++m)
#pragma unroll
      for (int r = 0; r < 16; ++r) sacc[m][r] = ex2(sacc[m][r] - mrun);

    // P -> bf16 B-frags via cvt_pk + permlane32_swap
    bf16x8 pf[4];
#pragma unroll
    for (int m = 0; m < 2; ++m)
#pragma unroll
      for (int sb = 0; sb < 2; ++sb) {
        unsigned p0 = pkbf(sacc[m][8 * sb + 0], sacc[m][8 * sb + 1]);
        unsigned p1 = pkbf(sacc[m][8 * sb + 2], sacc[m][8 * sb + 3]);
        unsigned p2 = pkbf(sacc[m][8 * sb + 4], sacc[m][8 * sb + 5]);
        unsigned p3 = pkbf(sacc[m][8 * sb + 6], sacc[m][8 * sb + 7]);
        plswap(p0, p2);
        plswap(p1, p3);
        union { unsigned u[4]; bf16x8 v; } fb;
        fb.u[0] = p0; fb.u[1] = p1; fb.u[2] = p2; fb.u[3] = p3;
        pf[2 * m + sb] = fb.v;
      }

    // O^T += V^T x P ; row-sum += ones x P (spans all 64 kv -> no shfl)
#pragma unroll
    for (int s = 0; s < 4; ++s) {
      lacc = __builtin_amdgcn_mfma_f32_32x32x16_bf16(ones, pf[s], lacc, 0, 0, 0);
#pragma unroll
      for (int mt = 0; mt < 2; ++mt) {
        const int row = mt * 32 + q31;
        const int sw = row & 7;
        bf16x8 vf = *(const bf16x8*)&Vs[cb + row * 64 + (((2 * s + hi) ^ sw) << 3)];
        oa[mt] = __builtin_amdgcn_mfma_f32_32x32x16_bf16(vf, pf[s], oa[mt], 0, 0, 0);
      }
    }
  }

  // epilogue: ctx[b, s=q0+q31, h*64+dk]
  const int bb2 = bh >> 4, h = bh & 15;
  const float rl = 1.0f / lacc[0];
  short* crow = ctx + ((long)(bb2 * S_ + q0 + q31)) * D_ + h * 64 + 4 * hi;
#pragma unroll
  for (int mt = 0; mt < 2; ++mt)
#pragma unroll
    for (int g = 0; g < 4; ++g) {
      s16x4 v4;
#pragma unroll
      for (int i = 0; i < 4; ++i) v4[i] = f2bf(oa[mt][4 * g + i] * rl);
      *(s16x4*)(crow + mt * 32 + g * 8) = v4;
    }
}

// ---------------- out = residual + LayerNorm(a) ----------------
template <int RES_BF16, int OUT_BF16>
__global__ __launch_bounds__(256)
void add_ln(const void* __restrict__ resv, const short* __restrict__ a,
            const float* __restrict__ gam, const float* __restrict__ bet,
            void* __restrict__ outv) {
  const int row = blockIdx.x, t = threadIdx.x;
  const int w = t >> 6, l = t & 63;
  const long roff = (long)row * D_;
  const int c = t * 4;
  s16x4 av = *(const s16x4*)(a + roff + c);
  float v0 = bf2f(av[0]), v1 = bf2f(av[1]), v2 = bf2f(av[2]), v3 = bf2f(av[3]);
  float s = v0 + v1 + v2 + v3;
#pragma unroll
  for (int mask = 1; mask < 64; mask <<= 1) s += __shfl_xor(s, mask, 64);
  __shared__ float r1[4], r2[4];
  if (l == 0) r1[w] = s;
  __syncthreads();
  float mu = (r1[0] + r1[1] + r1[2] + r1[3]) * (1.0f / D_);
  float d0 = v0 - mu, d1 = v1 - mu, d2 = v2 - mu, d3 = v3 - mu;
  float sq = d0 * d0 + d1 * d1 + d2 * d2 + d3 * d3;
#pragma unroll
  for (int mask = 1; mask < 64; mask <<= 1) sq += __shfl_xor(sq, mask, 64);
  if (l == 0) r2[w] = sq;
  __syncthreads();
  float var = (r2[0] + r2[1] + r2[2] + r2[3]) * (1.0f / D_);
  float rs = rsqrtf(var + 1e-5f);
  float res0, res1, res2, res3;
  if (RES_BF16) {
    s16x4 rv = *(const s16x4*)((const short*)resv + roff + c);
    res0 = bf2f(rv[0]); res1 = bf2f(rv[1]); res2 = bf2f(rv[2]); res3 = bf2f(rv[3]);
  } else {
    f32x4 rv = *(const f32x4*)((const float*)resv + roff + c);
    res0 = rv[0]; res1 = rv[1]; res2 = rv[2]; res3 = rv[3];
  }
  float o0 = res0 + d0 * rs * gam[c + 0] + bet[c + 0];
  float o1 = res1 + d1 * rs * gam[c + 1] + bet[c + 1];
  float o2 = res2 + d2 * rs * gam[c + 2] + bet[c + 2];
  float o3 = res3 + d3 * rs * gam[c + 3] + bet[c + 3];
  if (OUT_BF16) {
    s16x4 ov;
    ov[0] = f2bf(o0); ov[1] = f2bf(o1); ov[2] = f2bf(o2); ov[3] = f2bf(o3);
    *(s16x4*)((short*)outv + roff + c) = ov;
  } else {
    f32x4 ov;
    ov[0] = o0; ov[1] = o1; ov[2] = o2; ov[3] = o3;
    *(f32x4*)((float*)outv + roff + c) = ov;
  }
}

extern "C" void kernel_launch(void* const* d_in, const int* in_sizes, int n_in,
                              void* d_out, int out_size, void* d_ws, size_t ws_size,
                              hipStream_t stream) {
  (void)in_sizes; (void)n_in; (void)out_size; (void)ws_size;
  const float* x   = (const float*)d_in[0];
  const float* wq  = (const float*)d_in[1];
  const float* bq  = (const float*)d_in[2];
  const float* wk  = (const float*)d_in[3];
  const float* bk  = (const float*)d_in[4];
  const float* wv  = (const float*)d_in[5];
  const float* bv  = (const float*)d_in[6];
  const float* wo  = (const float*)d_in[7];
  const float* bo  = (const float*)d_in[8];
  const float* w1  = (const float*)d_in[9];
  const float* b1  = (const float*)d_in[10];
  const float* w2  = (const float*)d_in[11];
  const float* b2  = (const float*)d_in[12];
  const float* g1  = (const float*)d_in[13];
  const float* be1 = (const float*)d_in[14];
  const float* g2  = (const float*)d_in[15];
  const float* be2 = (const float*)d_in[16];

  char* ws = (char*)d_ws;
  const long MB = 1 << 20;
  short* xb    = (short*)(ws + 0 * MB);
  short* wqkvb = (short*)(ws + 16 * MB);
  short* wob   = (short*)(ws + 22 * MB);
  short* w1b   = (short*)(ws + 24 * MB);
  short* w2b   = (short*)(ws + 32 * MB);
  short* Qb    = (short*)(ws + 40 * MB);
  short* Kb    = (short*)(ws + 56 * MB);
  short* Vtb   = (short*)(ws + 72 * MB);   // V transposed [B,H,DK,S]
  short* ctxb  = (short*)(ws + 88 * MB);
  short* aout  = (short*)(ws + 40 * MB);   // reuse Q
  short* x1b   = (short*)(ws + 56 * MB);   // reuse K
  short* hid   = (short*)(ws + 88 * MB);   // reuse ctx (64MB, [88,152))
  short* ffb   = (short*)(ws + 72 * MB);   // reuse Vt

  auto cvt = [&](const float* in, short* out, long n) {
    cvt_kernel<<<dim3((unsigned)((n / 8 + 255) / 256)), dim3(256), 0, stream>>>(in, out, (int)n);
  };
  cvt(x, xb, (long)M_ * D_);
  cvt(wq, wqkvb + 0L * D_ * D_, (long)D_ * D_);
  cvt(wk, wqkvb + 1L * D_ * D_, (long)D_ * D_);
  cvt(wv, wqkvb + 2L * D_ * D_, (long)D_ * D_);
  cvt(wo, wob, (long)D_ * D_);
  cvt(w1, w1b, (long)DFF_ * D_);
  cvt(w2, w2b, (long)D_ * DFF_);

  // QKV projection (fused, N=3072): Q scaled log2e/8, V written transposed
  gemm8p<256, 2><<<dim3(3072 / 256, M_ / 256), 512, 0, stream>>>(
      xb, wqkvb, bq, bk, bv, nullptr, M_, 3072, D_, Qb, Kb, Vtb);

  attn_kernel<<<dim3(S_ / 256, B_ * H_), 512, 0, stream>>>(Qb, Kb, Vtb, ctxb);

  // O projection (N=1024 -> BN=128, grid = 256 blocks)
  gemm8p<128, 0><<<dim3(D_ / 128, M_ / 256), 512, 0, stream>>>(
      ctxb, wob, bo, nullptr, nullptr, aout, M_, D_, D_, nullptr, nullptr, nullptr);

  // x1 = x + LN(attn_out)
  add_ln<0, 1><<<dim3(M_), 256, 0, stream>>>(x, aout, g1, be1, x1b);

  // FFN
  gemm8p<256, 1><<<dim3(DFF_ / 256, M_ / 256), 512, 0, stream>>>(
      x1b, w1b, b1, nullptr, nullptr, hid, M_, DFF_, D_, nullptr, nullptr, nullptr);
  gemm8p<128, 0><<<dim3(D_ / 128, M_ / 256), 512, 0, stream>>>(
      hid, w2b, b2, nullptr, nullptr, ffb, M_, D_, DFF_, nullptr, nullptr, nullptr);

  // out = x1 + LN(ff)
  add_ln<1, 0><<<dim3(M_), 256, 0, stream>>>(x1b, ffb, g2, be2, d_out);
}